// Round 6
// baseline (258.032 us; speedup 1.0000x reference)
//
#include <hip/hip_runtime.h>
#include <math.h>

#define BATCH 16
#define HF 1024
#define WF 1024
#define HS 512
#define WS2 512
#define HC 256
#define WC 256
#define KMAX 32
#define CAP 16384
#define CROPSZ 160
#define CNT_STRIDE 16
#define NCHUNK 16
#define CHUNK 1024
#define LISTCAP 2048

// Guard-padded resized image: 5-px zero border so conv1's 5x5 s2 window can
// read unconditionally (SAME zero-padding == guard zeros).
#define IMGP_W 524
#define IMGP_H 524
#define IMGP_STRIDE (IMGP_W * IMGP_H)   // floats per batch = 274576

// cms = TWO pre-sigmoid partial planes (quad-split conv): plane A =
// bias + quads 0..3, plane B = quads 4..7. z = A + B; sigmoid applied by
// consumers (monotonic -> peak logic unchanged on z).
#define CMS_PLANE 1048576UL             // 16 * 65536 floats
#define THRESH_Z -1.38629436112f        // logit(0.2) = ln(0.25)

// ---- workspace byte offsets ----
#define OFF_IMGS 0UL                                   // 16*524*524*4 = 17572864
#define OFF_CMS  17572864UL                            // 2 planes * 4 MB
#define OFF_KEYS (OFF_CMS + 8388608UL)
#define OFF_CNT  (OFF_KEYS + 2097152UL)
#define OFF_CX   (OFF_CNT + 2048UL)
#define OFF_CY   (OFF_CX + 2048UL)
#define OFF_VLD  (OFF_CY + 2048UL)
#define OFF_CAND (OFF_VLD + 2048UL)                    // 16*16*32 u64 = 64 KB

// ---- output element offsets ----
#define OUT_CROPS 0
#define OUT_OFFS  13107200
#define OUT_VALS  13108224
#define OUT_VALID 13108736

// jax.image.resize(bilinear, antialias) at 0.5: 4-tap {1,3,3,1}/8, edge-renorm.
// Writes guard-padded layout; zeroes guards + done-counters every launch
// (workspace may be re-poisoned between iterations).
__global__ __launch_bounds__(256) void resize_kernel(const float* __restrict__ full,
                                                     float* __restrict__ imgs,
                                                     int* __restrict__ counts) {
    if (blockIdx.x == 0 && blockIdx.y == 0 && threadIdx.x < BATCH * CNT_STRIDE)
        counts[threadIdx.x] = 0;
    __shared__ float simg[10][1024];
    int tid = threadIdx.x;
    int y0 = blockIdx.x << 2;    // output rows y0..y0+3
    int b = blockIdx.y;
    const float* base = full + ((size_t)b << 20);
    float* ob = imgs + (size_t)b * IMGP_STRIDE;
    // ---- zero guards ----
    if (tid < 48) {              // left/right guards for this block's 4 rows
        int r = tid / 12, c = tid - (tid / 12) * 12;
        int col = c < 5 ? c : 512 + c;     // cols 0..4 and 517..523
        ob[(size_t)(5 + y0 + r) * IMGP_W + col] = 0.f;
    }
    if (blockIdx.x == 0)
        for (int i = tid; i < 5 * IMGP_W; i += 256) ob[i] = 0.f;         // top
    if (blockIdx.x == 127)
        for (int i = tid; i < 7 * IMGP_W; i += 256)
            ob[(size_t)517 * IMGP_W + i] = 0.f;                          // bottom
    // stage source rows 2*y0-1 .. 2*y0+8 (clamped; weight-0 rows are benign)
#pragma unroll
    for (int s = 0; s < 10; ++s) {
        int r = 2 * y0 - 1 + s;
        r = r < 0 ? 0 : (r > HF - 1 ? HF - 1 : r);
        ((float4*)simg[s])[tid] = ((const float4*)(base + r * WF))[tid];
    }
    __syncthreads();
    const float w4[4] = {0.125f, 0.375f, 0.375f, 0.125f};
#pragma unroll
    for (int p = 0; p < 2; ++p) {
        int x = tid + 256 * p;
        float wx[4];
        int rx[4];
        float sx = 0.f;
#pragma unroll
        for (int ii = 0; ii < 4; ++ii) {
            int c = 2 * x - 1 + ii;
            float wc = (c >= 0 && c < WF) ? w4[ii] : 0.f;
            wx[ii] = wc; sx += wc;
            rx[ii] = c < 0 ? 0 : (c >= WF ? WF - 1 : c);
        }
#pragma unroll
        for (int r = 0; r < 4; ++r) {
            int yy = y0 + r;
            float sy = 0.f;
            float wy[4];
#pragma unroll
            for (int j = 0; j < 4; ++j) {
                int rr = 2 * yy - 1 + j;
                float w = (rr >= 0 && rr < HF) ? w4[j] : 0.f;
                wy[j] = w; sy += w;
            }
            float acc = 0.f;
#pragma unroll
            for (int j = 0; j < 4; ++j) {
                float rowacc = 0.f;
                const float* sr = simg[2 * r + j];
#pragma unroll
                for (int ii = 0; ii < 4; ++ii) rowacc += wx[ii] * sr[rx[ii]];
                acc += wy[j] * rowacc;
            }
            ob[(size_t)(5 + yy) * IMGP_W + 5 + x] = acc * (1.f / (sy * sx));
        }
    }
}

// Fused conv1(5x5 s2, 1->32, relu) + conv2(5x5 s1, 32->1) — quad-split.
// Block = (32x32 cms tile, half): half 0 computes quads 0-3 (+bias) -> plane A,
// half 1 computes quads 4-7 -> plane B. No sigmoid (consumers apply it).
__global__ __launch_bounds__(256, 4) void conv_fused2_kernel(
    const float* __restrict__ imgs, const float* __restrict__ w1,
    const float* __restrict__ b1, const float* __restrict__ w2,
    const float* __restrict__ b2, float* __restrict__ cms) {
    __shared__ float4 sh[36][37];      // h quad tile, rows Y0-2 .. Y0+33
    int tid = threadIdx.x;
    int b = blockIdx.y >> 1;
    int half = blockIdx.y & 1;
    int q0 = half << 2;
    int Y0 = (blockIdx.x >> 3) << 5;   // 8x8 tiles of 32x32
    int X0 = (blockIdx.x & 7) << 5;
    const float* ib = imgs + (size_t)b * IMGP_STRIDE;

    // ---- conv1 work assignment (hoisted; quad-invariant) ----
    bool c1act = tid < 216;
    int ghy = tid / 6;                         // 0..35
    int ghx0 = (tid - ghy * 6) * 6;            // 0,6,..,30
    const float* gbase = ib + (size_t)(2 * Y0 + 2 * ghy) * IMGP_W
                            + (2 * X0 + 2 * ghx0);
    float4* shw = &sh[ghy][ghx0];
    bool rowok = (unsigned)(Y0 - 2 + ghy) < 256u;
    int gx0 = X0 - 2 + ghx0;

    // ---- conv2 work assignment (hoisted) ----
    int cx = tid & 31;                 // output column within tile
    int ry0 = (tid >> 5) << 2;         // output rows ry0..ry0+3
    const float4* hb = &sh[ry0][cx];
    float4 zv0 = make_float4(0.f, 0.f, 0.f, 0.f);
    float4 zv1 = zv0, zv2 = zv0, zv3 = zv0;

    for (int qi = 0; qi < 4; ++qi) {
        int q = q0 + qi;
        // w1 quad: uniform loads -> SGPRs
        float4 wq[25];
        const float4* w14 = (const float4*)w1;
#pragma unroll
        for (int t = 0; t < 25; ++t) wq[t] = w14[t * 8 + q];
        float4 bq = ((const float4*)b1)[q];

        // launder: opaque per-iteration offset so loads can't be hoisted
        int qoff = 0;
        asm volatile("" : "+v"(qoff));
        const float* gb = gbase + qoff;

        __syncthreads();   // prev conv2 reads of sh done before overwrite

        // ---- conv1: 6 h-pixels per active thread, global reads ----
        if (c1act) {
            float4 acc[6];
#pragma unroll
            for (int j = 0; j < 6; ++j) acc[j] = bq;
#pragma unroll
            for (int ky = 0; ky < 5; ++ky) {
                const float* rp = gb + ky * IMGP_W;
                float4 f0 = *(const float4*)(rp);
                float4 f1 = *(const float4*)(rp + 4);
                float4 f2 = *(const float4*)(rp + 8);
                float4 f3 = *(const float4*)(rp + 12);
                float f[16] = {f0.x, f0.y, f0.z, f0.w, f1.x, f1.y, f1.z, f1.w,
                               f2.x, f2.y, f2.z, f2.w, f3.x, f3.y, f3.z, f3.w};
#pragma unroll
                for (int j = 0; j < 6; ++j)
#pragma unroll
                    for (int kx = 0; kx < 5; ++kx) {
                        float v = f[2 * j + kx];
                        float4 w = wq[ky * 5 + kx];
                        acc[j].x += v * w.x; acc[j].y += v * w.y;
                        acc[j].z += v * w.z; acc[j].w += v * w.w;
                    }
            }
#pragma unroll
            for (int j = 0; j < 6; ++j) {
                float4 r;
                bool ok = rowok && ((unsigned)(gx0 + j) < 256u);
                r.x = ok ? fmaxf(acc[j].x, 0.f) : 0.f;
                r.y = ok ? fmaxf(acc[j].y, 0.f) : 0.f;
                r.z = ok ? fmaxf(acc[j].z, 0.f) : 0.f;
                r.w = ok ? fmaxf(acc[j].w, 0.f) : 0.f;
                shw[j] = r;
            }
        }

        // w2 quad (independent of LDS; before sync)
        const float4* w24 = (const float4*)w2;
#pragma unroll
        for (int t = 0; t < 25; ++t) wq[t] = w24[t * 8 + q];

        __syncthreads();

        // ---- conv2 partial: 4 outputs/thread, vertical register reuse ----
#pragma unroll
        for (int rr = 0; rr < 8; ++rr) {
#pragma unroll
            for (int kx = 0; kx < 5; ++kx) {
                float4 hv = hb[rr * 37 + kx];
#pragma unroll
                for (int j = 0; j < 4; ++j) {
                    int ky = rr - j;
                    if (ky < 0 || ky > 4) continue;
                    float4 w = wq[ky * 5 + kx];
                    if (j == 0) {
                        zv0.x += hv.x * w.x; zv0.y += hv.y * w.y;
                        zv0.z += hv.z * w.z; zv0.w += hv.w * w.w;
                    } else if (j == 1) {
                        zv1.x += hv.x * w.x; zv1.y += hv.y * w.y;
                        zv1.z += hv.z * w.z; zv1.w += hv.w * w.w;
                    } else if (j == 2) {
                        zv2.x += hv.x * w.x; zv2.y += hv.y * w.y;
                        zv2.z += hv.z * w.z; zv2.w += hv.w * w.w;
                    } else {
                        zv3.x += hv.x * w.x; zv3.y += hv.y * w.y;
                        zv3.z += hv.z * w.z; zv3.w += hv.w * w.w;
                    }
                }
            }
        }
    }

    float bb = half ? 0.f : b2[0];
    float z0 = bb + zv0.x + zv0.y + zv0.z + zv0.w;
    float z1 = bb + zv1.x + zv1.y + zv1.z + zv1.w;
    float z2 = bb + zv2.x + zv2.y + zv2.z + zv2.w;
    float z3 = bb + zv3.x + zv3.y + zv3.z + zv3.w;
    size_t ob = (size_t)half * CMS_PLANE + ((size_t)b << 16)
              + ((size_t)(Y0 + ry0) << 8) + (X0 + cx);
    cms[ob]       = z0;
    cms[ob + 256] = z1;
    cms[ob + 512] = z2;
    cms[ob + 768] = z3;
}

// R6: peak_scan + topk_a + topk_b fused. Block = (batch, 16-row stripe).
// Stage z-stripe (A+B) into LDS with +/-inf guard cols; rolling-max3 NMS
// (4 LDS reads/row/thread); peak keys -> LDS list via LDS atomics (cap 2048 =
// structural max: adjacent-row/col peaks require exact float ties); per-wave
// register top-32 over its quarter; cross-wave 128->32 on wave 0 -> cand.
// Last-arriving block per batch (device atomicAdd + __threadfence, split-K
// pattern) runs stage B inline: 512-cand top-32 + integral refinement.
__global__ __launch_bounds__(256) void peak_topk_kernel(
    const float* __restrict__ cms, int* __restrict__ done,
    unsigned long long* __restrict__ cand,
    float* __restrict__ out_off, float* __restrict__ out_vals,
    float* __restrict__ out_valid, float* __restrict__ ws_cx,
    float* __restrict__ ws_cy, float* __restrict__ ws_v) {
    int bidx = blockIdx.x;
    int b = bidx >> 4;
    int s = bidx & 15;
    int y0 = s << 4;                 // stripe rows y0..y0+15
    int tid = threadIdx.x;
    int lane = tid & 63;
    int wv = tid >> 6;
    __shared__ float zs[18][264];    // rows y0-1..y0+16; data cols 4..259
    __shared__ unsigned long long list[LISTCAP];
    __shared__ unsigned long long wtop[4][KMAX];
    __shared__ int lcnt;
    __shared__ int flag;
    if (tid == 0) { lcnt = 0; flag = 0; }
    if (tid < 36) {                  // +/-inf guard cols 3 and 260
        int r = tid >> 1;
        zs[r][(tid & 1) ? 3 : 260] = -INFINITY;
    }
    const float* pa = cms + ((size_t)b << 16);
    const float* pb = cms + CMS_PLANE + ((size_t)b << 16);
    for (int i = tid; i < 18 * 64; i += 256) {
        int r = i >> 6;              // LDS row 0..17
        int c4 = i & 63;             // float4 col
        int yy = y0 - 1 + r;
        float4 v4 = make_float4(-INFINITY, -INFINITY, -INFINITY, -INFINITY);
        if ((unsigned)yy < 256u) {
            float4 a  = ((const float4*)(pa + ((size_t)yy << 8)))[c4];
            float4 bv = ((const float4*)(pb + ((size_t)yy << 8)))[c4];
            v4 = make_float4(a.x + bv.x, a.y + bv.y, a.z + bv.z, a.w + bv.w);
        }
        ((float4*)&zs[r][4])[c4] = v4;   // col 4 => 16B-aligned float4 store
    }
    __syncthreads();
    {
        int x = tid;                 // column 0..255
        float m0 = fmaxf(fmaxf(zs[0][3 + x], zs[0][4 + x]), zs[0][5 + x]);
        float m1 = fmaxf(fmaxf(zs[1][3 + x], zs[1][4 + x]), zs[1][5 + x]);
#pragma unroll
        for (int r = 0; r < 16; ++r) {
            float m2 = fmaxf(fmaxf(zs[r + 2][3 + x], zs[r + 2][4 + x]),
                             zs[r + 2][5 + x]);
            float c = zs[r + 1][4 + x];
            bool peak = (c > THRESH_Z) && (c >= m0) && (c >= m1) && (c >= m2);
            if (peak) {
                int pos = atomicAdd(&lcnt, 1);
                if (pos < LISTCAP) {
                    unsigned u = __float_as_uint(c);
                    u = (u & 0x80000000u) ? ~u : (u | 0x80000000u);
                    int idx = (y0 + r) * WC + x;
                    list[pos] = ((unsigned long long)u << 32) |
                                (unsigned long long)(0xFFFFFFFFu - (unsigned)idx);
                }
            }
            m0 = m1; m1 = m2;
        }
    }
    __syncthreads();
    int n = lcnt; if (n > LISTCAP) n = LISTCAP;
    // per-wave top-32 over its quarter of the list (slots tid + j*256)
    unsigned long long v[8];
#pragma unroll
    for (int j = 0; j < 8; ++j) {
        int i = tid + (j << 8);
        v[j] = (i < n) ? list[i] : 0ULL;
    }
    int kw = 0;
    for (; kw < KMAX; ++kw) {
        unsigned long long best = v[0];
#pragma unroll
        for (int j = 1; j < 8; ++j) best = v[j] > best ? v[j] : best;
#pragma unroll
        for (int st = 1; st < 64; st <<= 1) {
            unsigned long long o = __shfl_xor(best, st, 64);
            if (o > best) best = o;
        }
        if (best == 0ULL) break;
        if (lane == 0) wtop[wv][kw] = best;
#pragma unroll
        for (int j = 0; j < 8; ++j) if (v[j] == best) v[j] = 0ULL;
    }
    if (lane >= kw && lane < KMAX) wtop[wv][lane] = 0ULL;
    __syncthreads();
    // final top-32 of 128 on wave 0 -> cand
    unsigned long long* ob = cand + (size_t)(b * NCHUNK + s) * KMAX;
    if (wv == 0) {
        unsigned long long u0 = ((unsigned long long*)wtop)[lane];
        unsigned long long u1 = ((unsigned long long*)wtop)[lane + 64];
        int k = 0;
        for (; k < KMAX; ++k) {
            unsigned long long best = u0 > u1 ? u0 : u1;
#pragma unroll
            for (int st = 1; st < 64; st <<= 1) {
                unsigned long long o = __shfl_xor(best, st, 64);
                if (o > best) best = o;
            }
            if (best == 0ULL) break;
            if (lane == 0) ob[k] = best;
            if (u0 == best) u0 = 0ULL;
            if (u1 == best) u1 = 0ULL;
        }
        if (lane >= k && lane < KMAX) ob[lane] = 0ULL;
    }
    __syncthreads();                 // ob stores issued before signaling
    if (tid == 0) {
        __threadfence();             // release: cand visible device-wide
        int old = atomicAdd(&done[b * CNT_STRIDE], 1);
        flag = (old == 15) ? 1 : 0;
    }
    __syncthreads();
    if (!flag || tid >= 64) return;
    __threadfence();                 // acquire: see other blocks' cand
    // ---- stage B: top-32 of 512 candidates + integral refinement ----
    unsigned long long vb[8];
#pragma unroll
    for (int j = 0; j < 8; ++j)
        vb[j] = cand[(size_t)b * 512 + tid + (j << 6)];
    unsigned long long mysel = 0ULL;
    for (int k = 0; k < KMAX; ++k) {
        unsigned long long best = vb[0];
#pragma unroll
        for (int j = 1; j < 8; ++j) best = vb[j] > best ? vb[j] : best;
#pragma unroll
        for (int st = 1; st < 64; st <<= 1) {
            unsigned long long o = __shfl_xor(best, st, 64);
            if (o > best) best = o;
        }
        if (best == 0ULL) break;
        if (tid == k) mysel = best;
#pragma unroll
        for (int j = 0; j < 8; ++j) if (vb[j] == best) vb[j] = 0ULL;
    }
    if (tid < KMAX) {
        unsigned long long key = mysel;
        bool valid = key != 0ULL;
        float cx = 80.f, cy = 80.f, val = 0.f;
        if (valid) {
            unsigned f = (unsigned)(key >> 32);
            unsigned u = (f & 0x80000000u) ? (f & 0x7FFFFFFFu) : ~f;
            float z = __uint_as_float(u);
            val = 1.f / (1.f + expf(-z));
            int idx = (int)(0xFFFFFFFFu - (unsigned)(key & 0xFFFFFFFFULL));
            int py = idx >> 8, px = idx & 255;
            float gv = 1e-12f, sdx = 0.f, sdy = 0.f;
#pragma unroll
            for (int oy = -2; oy <= 2; ++oy)
#pragma unroll
                for (int ox = -2; ox <= 2; ++ox) {
                    int yy = py + oy, xx = px + ox;
                    if (yy < 0 || yy >= HC || xx < 0 || xx >= WC) continue;
                    float zz = pa[yy * WC + xx] + pb[yy * WC + xx];
                    float pv = 1.f / (1.f + expf(-zz));
                    gv += pv; sdx += pv * (float)ox; sdy += pv * (float)oy;
                }
            float dx = sdx / gv, dy = sdy / gv;
            cx = ((float)px + dx) * 4.f;
            cy = ((float)py + dy) * 4.f;
        }
        int o = b * KMAX + tid;
        out_off[o * 2 + 0] = cx - 80.f;
        out_off[o * 2 + 1] = cy - 80.f;
        out_vals[o] = val;
        out_valid[o] = valid ? 1.f : 0.f;
        ws_cx[o] = cx; ws_cy[o] = cy; ws_v[o] = valid ? 1.f : 0.f;
    }
}

// 4 output rows per thread; wy crop-constant -> 5 row-interps serve 4 rows.
__global__ __launch_bounds__(256) void crop_kernel(
    const float* __restrict__ full, const float* __restrict__ ws_cx,
    const float* __restrict__ ws_cy, const float* __restrict__ ws_v,
    float* __restrict__ out_crops) {
    int bidx = blockIdx.x;
    int cid = bidx / 25;
    int p = (bidx - cid * 25) * 256 + threadIdx.x;   // 0..6399
    int b = cid >> 5;
    float cx = ws_cx[cid], cy = ws_cy[cid], v = ws_v[cid];
    int rg = p / CROPSZ;             // row group 0..39
    int col = p - rg * CROPSZ;
    int r0 = rg << 2;                // output rows r0..r0+3
    float sx = cx - 79.5f + (float)col;
    float x0f = floorf(sx);
    float wx = sx - x0f;
    int x0 = (int)x0f;
    int xi0 = min(max(x0, 0), WF - 1);
    int xi1 = min(max(x0 + 1, 0), WF - 1);
    float syb = cy - 79.5f + (float)r0;
    float y0f = floorf(syb);
    float wy = syb - y0f;
    int y0 = (int)y0f;
    const float* base = full + ((size_t)b << 20);
    float rv[5];
#pragma unroll
    for (int i = 0; i < 5; ++i) {
        int yy = min(max(y0 + i, 0), HF - 1);
        float a = base[yy * WF + xi0];
        float c = base[yy * WF + xi1];
        rv[i] = a * (1.f - wx) + c * wx;
    }
    bool xin = (sx >= 0.f && sx <= (float)(WF - 1));
    size_t ob = (size_t)cid * (CROPSZ * CROPSZ) + r0 * CROPSZ + col;
#pragma unroll
    for (int i = 0; i < 4; ++i) {
        float sy = syb + (float)i;
        float val = rv[i] * (1.f - wy) + rv[i + 1] * wy;
        float inr = (xin && sy >= 0.f && sy <= (float)(HF - 1)) ? 1.f : 0.f;
        out_crops[ob + i * CROPSZ] = val * inr * v;
    }
}

extern "C" void kernel_launch(void* const* d_in, const int* in_sizes, int n_in,
                              void* d_out, int out_size, void* d_ws, size_t ws_size,
                              hipStream_t stream) {
    const float* full = (const float*)d_in[0];
    const float* w1   = (const float*)d_in[1];
    const float* b1   = (const float*)d_in[2];
    const float* w2   = (const float*)d_in[3];
    const float* b2   = (const float*)d_in[4];

    char* ws = (char*)d_ws;
    float* imgs = (float*)(ws + OFF_IMGS);
    float* cms  = (float*)(ws + OFF_CMS);
    int* counts = (int*)(ws + OFF_CNT);
    float* ws_cx = (float*)(ws + OFF_CX);
    float* ws_cy = (float*)(ws + OFF_CY);
    float* ws_v  = (float*)(ws + OFF_VLD);
    unsigned long long* cand = (unsigned long long*)(ws + OFF_CAND);

    float* out = (float*)d_out;
    float* out_crops = out + OUT_CROPS;
    float* out_off   = out + OUT_OFFS;
    float* out_vals  = out + OUT_VALS;
    float* out_valid = out + OUT_VALID;

    hipLaunchKernelGGL(resize_kernel, dim3(128, 16), dim3(256), 0, stream,
                       full, imgs, counts);

    hipLaunchKernelGGL(conv_fused2_kernel, dim3(64, 32), dim3(256), 0, stream,
                       imgs, w1, b1, w2, b2, cms);

    hipLaunchKernelGGL(peak_topk_kernel, dim3(256), dim3(256), 0, stream,
                       cms, counts, cand, out_off, out_vals, out_valid,
                       ws_cx, ws_cy, ws_v);

    hipLaunchKernelGGL(crop_kernel, dim3(12800), dim3(256), 0, stream,
                       full, ws_cx, ws_cy, ws_v, out_crops);
}

// Round 7
// 256.421 us; speedup vs baseline: 1.0063x; 1.0063x over previous
//
#include <hip/hip_runtime.h>
#include <math.h>

#define BATCH 16
#define HF 1024
#define WF 1024
#define HS 512
#define WS2 512
#define HC 256
#define WC 256
#define KMAX 32
#define CAP 16384
#define CROPSZ 160
#define CNT_STRIDE 16
#define NCHUNK 16
#define CHUNK 1024
#define LISTCAP 2048

// Guard-padded resized image: 5-px zero border so conv1's 5x5 s2 window can
// read unconditionally (SAME zero-padding == guard zeros).
#define IMGP_W 524
#define IMGP_H 524
#define IMGP_STRIDE (IMGP_W * IMGP_H)   // floats per batch = 274576

// cms = TWO pre-sigmoid partial planes (quad-split conv): plane A =
// bias + quads 0..3, plane B = quads 4..7. z = A + B; sigmoid applied by
// consumers (monotonic -> peak logic unchanged on z).
#define CMS_PLANE 1048576UL             // 16 * 65536 floats
#define THRESH_Z -1.38629436112f        // logit(0.2) = ln(0.25)

// ---- workspace byte offsets ----
#define OFF_IMGS 0UL                                   // 16*524*524*4 = 17572864
#define OFF_CMS  17572864UL                            // 2 planes * 4 MB
#define OFF_KEYS (OFF_CMS + 8388608UL)
#define OFF_CNT  (OFF_KEYS + 2097152UL)
#define OFF_CX   (OFF_CNT + 2048UL)
#define OFF_CY   (OFF_CX + 2048UL)
#define OFF_VLD  (OFF_CY + 2048UL)
#define OFF_CAND (OFF_VLD + 2048UL)                    // 16*16*32 u64 = 64 KB

// ---- output element offsets ----
#define OUT_CROPS 0
#define OUT_OFFS  13107200
#define OUT_VALS  13108224
#define OUT_VALID 13108736

// jax.image.resize(bilinear, antialias) at 0.5: 4-tap {1,3,3,1}/8, edge-renorm.
// Writes guard-padded layout; zeroes guards + done-counters every launch
// (workspace may be re-poisoned between iterations).
__global__ __launch_bounds__(256) void resize_kernel(const float* __restrict__ full,
                                                     float* __restrict__ imgs,
                                                     int* __restrict__ counts) {
    if (blockIdx.x == 0 && blockIdx.y == 0 && threadIdx.x < BATCH * CNT_STRIDE)
        counts[threadIdx.x] = 0;
    __shared__ float simg[10][1024];
    int tid = threadIdx.x;
    int y0 = blockIdx.x << 2;    // output rows y0..y0+3
    int b = blockIdx.y;
    const float* base = full + ((size_t)b << 20);
    float* ob = imgs + (size_t)b * IMGP_STRIDE;
    // ---- zero guards ----
    if (tid < 48) {              // left/right guards for this block's 4 rows
        int r = tid / 12, c = tid - (tid / 12) * 12;
        int col = c < 5 ? c : 512 + c;     // cols 0..4 and 517..523
        ob[(size_t)(5 + y0 + r) * IMGP_W + col] = 0.f;
    }
    if (blockIdx.x == 0)
        for (int i = tid; i < 5 * IMGP_W; i += 256) ob[i] = 0.f;         // top
    if (blockIdx.x == 127)
        for (int i = tid; i < 7 * IMGP_W; i += 256)
            ob[(size_t)517 * IMGP_W + i] = 0.f;                          // bottom
    // stage source rows 2*y0-1 .. 2*y0+8 (clamped; weight-0 rows are benign)
#pragma unroll
    for (int s = 0; s < 10; ++s) {
        int r = 2 * y0 - 1 + s;
        r = r < 0 ? 0 : (r > HF - 1 ? HF - 1 : r);
        ((float4*)simg[s])[tid] = ((const float4*)(base + r * WF))[tid];
    }
    __syncthreads();
    const float w4[4] = {0.125f, 0.375f, 0.375f, 0.125f};
#pragma unroll
    for (int p = 0; p < 2; ++p) {
        int x = tid + 256 * p;
        float wx[4];
        int rx[4];
        float sx = 0.f;
#pragma unroll
        for (int ii = 0; ii < 4; ++ii) {
            int c = 2 * x - 1 + ii;
            float wc = (c >= 0 && c < WF) ? w4[ii] : 0.f;
            wx[ii] = wc; sx += wc;
            rx[ii] = c < 0 ? 0 : (c >= WF ? WF - 1 : c);
        }
#pragma unroll
        for (int r = 0; r < 4; ++r) {
            int yy = y0 + r;
            float sy = 0.f;
            float wy[4];
#pragma unroll
            for (int j = 0; j < 4; ++j) {
                int rr = 2 * yy - 1 + j;
                float w = (rr >= 0 && rr < HF) ? w4[j] : 0.f;
                wy[j] = w; sy += w;
            }
            float acc = 0.f;
#pragma unroll
            for (int j = 0; j < 4; ++j) {
                float rowacc = 0.f;
                const float* sr = simg[2 * r + j];
#pragma unroll
                for (int ii = 0; ii < 4; ++ii) rowacc += wx[ii] * sr[rx[ii]];
                acc += wy[j] * rowacc;
            }
            ob[(size_t)(5 + yy) * IMGP_W + 5 + x] = acc * (1.f / (sy * sx));
        }
    }
}

// compile-time float4 component selection (replaces the f[16] staging array)
#define C4(vec, c) ((c) == 0 ? (vec).x : (c) == 1 ? (vec).y : (c) == 2 ? (vec).z : (vec).w)
#define FELT(i) ((i) < 4 ? C4(f0, (i)) : (i) < 8 ? C4(f1, (i) - 4) \
                 : (i) < 12 ? C4(f2, (i) - 8) : C4(f3, (i) - 12))

// Fused conv1(5x5 s2, 1->32, relu) + conv2(5x5 s1, 32->1) — quad-split.
// Block = (32x32 cms tile, half): half 0 computes quads 0-3 (+bias) -> plane A,
// half 1 computes quads 4-7 -> plane B. No sigmoid (consumers apply it).
__global__ __launch_bounds__(256, 4) void conv_fused2_kernel(
    const float* __restrict__ imgs, const float* __restrict__ w1,
    const float* __restrict__ b1, const float* __restrict__ w2,
    const float* __restrict__ b2, float* __restrict__ cms) {
    __shared__ float4 sh[36][37];      // h quad tile, rows Y0-2 .. Y0+33
    int tid = threadIdx.x;
    int b = blockIdx.y >> 1;
    int half = blockIdx.y & 1;
    int q0 = half << 2;
    int Y0 = (blockIdx.x >> 3) << 5;   // 8x8 tiles of 32x32
    int X0 = (blockIdx.x & 7) << 5;
    const float* ib = imgs + (size_t)b * IMGP_STRIDE;

    // ---- conv1 work assignment (hoisted; quad-invariant) ----
    bool c1act = tid < 216;
    int ghy = tid / 6;                         // 0..35
    int ghx0 = (tid - ghy * 6) * 6;            // 0,6,..,30
    const float* gbase = ib + (size_t)(2 * Y0 + 2 * ghy) * IMGP_W
                            + (2 * X0 + 2 * ghx0);
    float4* shw = &sh[ghy][ghx0];
    bool rowok = (unsigned)(Y0 - 2 + ghy) < 256u;
    int gx0 = X0 - 2 + ghx0;

    // ---- conv2 work assignment (hoisted) ----
    int cx = tid & 31;                 // output column within tile
    int ry0 = (tid >> 5) << 2;         // output rows ry0..ry0+3
    const float4* hb = &sh[ry0][cx];
    float4 zv0 = make_float4(0.f, 0.f, 0.f, 0.f);
    float4 zv1 = zv0, zv2 = zv0, zv3 = zv0;

    for (int qi = 0; qi < 4; ++qi) {
        int q = q0 + qi;
        // w1 quad: uniform loads -> SGPRs
        float4 wq[25];
        const float4* w14 = (const float4*)w1;
#pragma unroll
        for (int t = 0; t < 25; ++t) wq[t] = w14[t * 8 + q];
        float4 bq = ((const float4*)b1)[q];

        // launder: opaque per-iteration offset so loads can't be hoisted
        int qoff = 0;
        asm volatile("" : "+v"(qoff));
        const float* gb = gbase + qoff;

        __syncthreads();   // prev conv2 reads of sh done before overwrite

        // ---- conv1: 6 h-pixels per active thread, global reads ----
        if (c1act) {
            float4 acc[6];
#pragma unroll
            for (int j = 0; j < 6; ++j) acc[j] = bq;
#pragma unroll
            for (int ky = 0; ky < 5; ++ky) {
                const float* rp = gb + ky * IMGP_W;
                float4 f0 = *(const float4*)(rp);
                float4 f1 = *(const float4*)(rp + 4);
                float4 f2 = *(const float4*)(rp + 8);
                float4 f3 = *(const float4*)(rp + 12);
#pragma unroll
                for (int j = 0; j < 6; ++j)
#pragma unroll
                    for (int kx = 0; kx < 5; ++kx) {
                        float v = FELT(2 * j + kx);
                        float4 w = wq[ky * 5 + kx];
                        acc[j].x += v * w.x; acc[j].y += v * w.y;
                        acc[j].z += v * w.z; acc[j].w += v * w.w;
                    }
            }
#pragma unroll
            for (int j = 0; j < 6; ++j) {
                float4 r;
                bool ok = rowok && ((unsigned)(gx0 + j) < 256u);
                r.x = ok ? fmaxf(acc[j].x, 0.f) : 0.f;
                r.y = ok ? fmaxf(acc[j].y, 0.f) : 0.f;
                r.z = ok ? fmaxf(acc[j].z, 0.f) : 0.f;
                r.w = ok ? fmaxf(acc[j].w, 0.f) : 0.f;
                shw[j] = r;
            }
        }

        // w2 quad (independent of LDS; before sync)
        const float4* w24 = (const float4*)w2;
#pragma unroll
        for (int t = 0; t < 25; ++t) wq[t] = w24[t * 8 + q];

        __syncthreads();

        // ---- conv2 partial: 4 outputs/thread, vertical register reuse ----
#pragma unroll
        for (int rr = 0; rr < 8; ++rr) {
#pragma unroll
            for (int kx = 0; kx < 5; ++kx) {
                float4 hv = hb[rr * 37 + kx];
#pragma unroll
                for (int j = 0; j < 4; ++j) {
                    int ky = rr - j;
                    if (ky < 0 || ky > 4) continue;
                    float4 w = wq[ky * 5 + kx];
                    if (j == 0) {
                        zv0.x += hv.x * w.x; zv0.y += hv.y * w.y;
                        zv0.z += hv.z * w.z; zv0.w += hv.w * w.w;
                    } else if (j == 1) {
                        zv1.x += hv.x * w.x; zv1.y += hv.y * w.y;
                        zv1.z += hv.z * w.z; zv1.w += hv.w * w.w;
                    } else if (j == 2) {
                        zv2.x += hv.x * w.x; zv2.y += hv.y * w.y;
                        zv2.z += hv.z * w.z; zv2.w += hv.w * w.w;
                    } else {
                        zv3.x += hv.x * w.x; zv3.y += hv.y * w.y;
                        zv3.z += hv.z * w.z; zv3.w += hv.w * w.w;
                    }
                }
            }
        }
    }

    float bb = half ? 0.f : b2[0];
    float z0 = bb + zv0.x + zv0.y + zv0.z + zv0.w;
    float z1 = bb + zv1.x + zv1.y + zv1.z + zv1.w;
    float z2 = bb + zv2.x + zv2.y + zv2.z + zv2.w;
    float z3 = bb + zv3.x + zv3.y + zv3.z + zv3.w;
    size_t ob = (size_t)half * CMS_PLANE + ((size_t)b << 16)
              + ((size_t)(Y0 + ry0) << 8) + (X0 + cx);
    cms[ob]       = z0;
    cms[ob + 256] = z1;
    cms[ob + 512] = z2;
    cms[ob + 768] = z3;
}

// peak_scan + topk fused (R6). Block = (batch, 16-row stripe); z staged in
// LDS; rolling-max3 NMS; LDS peak list; per-wave register top-32; cross-wave
// 128->32; last block per batch (atomicAdd + threadfence) runs stage B inline.
__global__ __launch_bounds__(256) void peak_topk_kernel(
    const float* __restrict__ cms, int* __restrict__ done,
    unsigned long long* __restrict__ cand,
    float* __restrict__ out_off, float* __restrict__ out_vals,
    float* __restrict__ out_valid, float* __restrict__ ws_cx,
    float* __restrict__ ws_cy, float* __restrict__ ws_v) {
    int bidx = blockIdx.x;
    int b = bidx >> 4;
    int s = bidx & 15;
    int y0 = s << 4;                 // stripe rows y0..y0+15
    int tid = threadIdx.x;
    int lane = tid & 63;
    int wv = tid >> 6;
    __shared__ float zs[18][264];    // rows y0-1..y0+16; data cols 4..259
    __shared__ unsigned long long list[LISTCAP];
    __shared__ unsigned long long wtop[4][KMAX];
    __shared__ int lcnt;
    __shared__ int flag;
    if (tid == 0) { lcnt = 0; flag = 0; }
    if (tid < 36) {                  // +/-inf guard cols 3 and 260
        int r = tid >> 1;
        zs[r][(tid & 1) ? 3 : 260] = -INFINITY;
    }
    const float* pa = cms + ((size_t)b << 16);
    const float* pb = cms + CMS_PLANE + ((size_t)b << 16);
    for (int i = tid; i < 18 * 64; i += 256) {
        int r = i >> 6;              // LDS row 0..17
        int c4 = i & 63;             // float4 col
        int yy = y0 - 1 + r;
        float4 v4 = make_float4(-INFINITY, -INFINITY, -INFINITY, -INFINITY);
        if ((unsigned)yy < 256u) {
            float4 a  = ((const float4*)(pa + ((size_t)yy << 8)))[c4];
            float4 bv = ((const float4*)(pb + ((size_t)yy << 8)))[c4];
            v4 = make_float4(a.x + bv.x, a.y + bv.y, a.z + bv.z, a.w + bv.w);
        }
        ((float4*)&zs[r][4])[c4] = v4;   // col 4 => 16B-aligned float4 store
    }
    __syncthreads();
    {
        int x = tid;                 // column 0..255
        float m0 = fmaxf(fmaxf(zs[0][3 + x], zs[0][4 + x]), zs[0][5 + x]);
        float m1 = fmaxf(fmaxf(zs[1][3 + x], zs[1][4 + x]), zs[1][5 + x]);
#pragma unroll
        for (int r = 0; r < 16; ++r) {
            float m2 = fmaxf(fmaxf(zs[r + 2][3 + x], zs[r + 2][4 + x]),
                             zs[r + 2][5 + x]);
            float c = zs[r + 1][4 + x];
            bool peak = (c > THRESH_Z) && (c >= m0) && (c >= m1) && (c >= m2);
            if (peak) {
                int pos = atomicAdd(&lcnt, 1);
                if (pos < LISTCAP) {
                    unsigned u = __float_as_uint(c);
                    u = (u & 0x80000000u) ? ~u : (u | 0x80000000u);
                    int idx = (y0 + r) * WC + x;
                    list[pos] = ((unsigned long long)u << 32) |
                                (unsigned long long)(0xFFFFFFFFu - (unsigned)idx);
                }
            }
            m0 = m1; m1 = m2;
        }
    }
    __syncthreads();
    int n = lcnt; if (n > LISTCAP) n = LISTCAP;
    // per-wave top-32 over its quarter of the list (slots tid + j*256)
    unsigned long long v[8];
#pragma unroll
    for (int j = 0; j < 8; ++j) {
        int i = tid + (j << 8);
        v[j] = (i < n) ? list[i] : 0ULL;
    }
    int kw = 0;
    for (; kw < KMAX; ++kw) {
        unsigned long long best = v[0];
#pragma unroll
        for (int j = 1; j < 8; ++j) best = v[j] > best ? v[j] : best;
#pragma unroll
        for (int st = 1; st < 64; st <<= 1) {
            unsigned long long o = __shfl_xor(best, st, 64);
            if (o > best) best = o;
        }
        if (best == 0ULL) break;
        if (lane == 0) wtop[wv][kw] = best;
#pragma unroll
        for (int j = 0; j < 8; ++j) if (v[j] == best) v[j] = 0ULL;
    }
    if (lane >= kw && lane < KMAX) wtop[wv][lane] = 0ULL;
    __syncthreads();
    // final top-32 of 128 on wave 0 -> cand
    unsigned long long* ob = cand + (size_t)(b * NCHUNK + s) * KMAX;
    if (wv == 0) {
        unsigned long long u0 = ((unsigned long long*)wtop)[lane];
        unsigned long long u1 = ((unsigned long long*)wtop)[lane + 64];
        int k = 0;
        for (; k < KMAX; ++k) {
            unsigned long long best = u0 > u1 ? u0 : u1;
#pragma unroll
            for (int st = 1; st < 64; st <<= 1) {
                unsigned long long o = __shfl_xor(best, st, 64);
                if (o > best) best = o;
            }
            if (best == 0ULL) break;
            if (lane == 0) ob[k] = best;
            if (u0 == best) u0 = 0ULL;
            if (u1 == best) u1 = 0ULL;
        }
        if (lane >= k && lane < KMAX) ob[lane] = 0ULL;
    }
    __syncthreads();                 // ob stores issued before signaling
    if (tid == 0) {
        __threadfence();             // release: cand visible device-wide
        int old = atomicAdd(&done[b * CNT_STRIDE], 1);
        flag = (old == 15) ? 1 : 0;
    }
    __syncthreads();
    if (!flag || tid >= 64) return;
    __threadfence();                 // acquire: see other blocks' cand
    // ---- stage B: top-32 of 512 candidates + integral refinement ----
    unsigned long long vb[8];
#pragma unroll
    for (int j = 0; j < 8; ++j)
        vb[j] = cand[(size_t)b * 512 + tid + (j << 6)];
    unsigned long long mysel = 0ULL;
    for (int k = 0; k < KMAX; ++k) {
        unsigned long long best = vb[0];
#pragma unroll
        for (int j = 1; j < 8; ++j) best = vb[j] > best ? vb[j] : best;
#pragma unroll
        for (int st = 1; st < 64; st <<= 1) {
            unsigned long long o = __shfl_xor(best, st, 64);
            if (o > best) best = o;
        }
        if (best == 0ULL) break;
        if (tid == k) mysel = best;
#pragma unroll
        for (int j = 0; j < 8; ++j) if (vb[j] == best) vb[j] = 0ULL;
    }
    if (tid < KMAX) {
        unsigned long long key = mysel;
        bool valid = key != 0ULL;
        float cx = 80.f, cy = 80.f, val = 0.f;
        if (valid) {
            unsigned f = (unsigned)(key >> 32);
            unsigned u = (f & 0x80000000u) ? (f & 0x7FFFFFFFu) : ~f;
            float z = __uint_as_float(u);
            val = 1.f / (1.f + expf(-z));
            int idx = (int)(0xFFFFFFFFu - (unsigned)(key & 0xFFFFFFFFULL));
            int py = idx >> 8, px = idx & 255;
            float gv = 1e-12f, sdx = 0.f, sdy = 0.f;
#pragma unroll
            for (int oy = -2; oy <= 2; ++oy)
#pragma unroll
                for (int ox = -2; ox <= 2; ++ox) {
                    int yy = py + oy, xx = px + ox;
                    if (yy < 0 || yy >= HC || xx < 0 || xx >= WC) continue;
                    float zz = pa[yy * WC + xx] + pb[yy * WC + xx];
                    float pv = 1.f / (1.f + expf(-zz));
                    gv += pv; sdx += pv * (float)ox; sdy += pv * (float)oy;
                }
            float dx = sdx / gv, dy = sdy / gv;
            cx = ((float)px + dx) * 4.f;
            cy = ((float)py + dy) * 4.f;
        }
        int o = b * KMAX + tid;
        out_off[o * 2 + 0] = cx - 80.f;
        out_off[o * 2 + 1] = cy - 80.f;
        out_vals[o] = val;
        out_valid[o] = valid ? 1.f : 0.f;
        ws_cx[o] = cx; ws_cy[o] = cy; ws_v[o] = valid ? 1.f : 0.f;
    }
}

// R7: thread = 4 cols x 5 rows (20 px). Integer col/row offsets preserve the
// bilinear fraction, so wx/wy are shared across the whole register tile:
// 5 clamped scalar taps/row serve 4 cols, 6 tap-rows serve 5 output rows.
// 30 loads + ~75 VALU + 5 aligned float4 stores per 20 px (was 50 loads +
// 150 VALU + 20 scalar stores). 5 blocks per crop, exact.
__global__ __launch_bounds__(256) void crop_kernel(
    const float* __restrict__ full, const float* __restrict__ ws_cx,
    const float* __restrict__ ws_cy, const float* __restrict__ ws_v,
    float* __restrict__ out_crops) {
    int bidx = blockIdx.x;
    int cid = bidx / 5;
    int g = (bidx - cid * 5) * 256 + threadIdx.x;   // 0..1279
    int b = cid >> 5;
    float cx = ws_cx[cid], cy = ws_cy[cid], v = ws_v[cid];
    int rowg = g / 40;               // 0..31 -> rows rowg*5 .. +4
    int colg = g - rowg * 40;        // 0..39 -> cols colg*4 .. +3
    int r0 = rowg * 5;
    int c0 = colg << 2;
    float sxb = cx - 79.5f + (float)c0;
    float x0f = floorf(sxb);
    float wx = sxb - x0f;
    int x0 = (int)x0f;
    float syb = cy - 79.5f + (float)r0;
    float y0f = floorf(syb);
    float wy = syb - y0f;
    int y0 = (int)y0f;
    const float* base = full + ((size_t)b << 20);
    float t[6][5];                   // fully unrolled -> registers
#pragma unroll
    for (int i = 0; i < 6; ++i) {
        int yy = min(max(y0 + i, 0), HF - 1);
        const float* rp = base + yy * WF;
#pragma unroll
        for (int k = 0; k < 5; ++k) {
            int xx = min(max(x0 + k, 0), WF - 1);
            t[i][k] = rp[xx];
        }
    }
    float omwx = 1.f - wx, omwy = 1.f - wy;
    float hz[6][4];
#pragma unroll
    for (int i = 0; i < 6; ++i)
#pragma unroll
        for (int c = 0; c < 4; ++c)
            hz[i][c] = t[i][c] * omwx + t[i][c + 1] * wx;
    float cin[4];
#pragma unroll
    for (int c = 0; c < 4; ++c) {
        float sx = sxb + (float)c;
        cin[c] = (sx >= 0.f && sx <= (float)(WF - 1)) ? v : 0.f;
    }
    size_t ob = (size_t)cid * (CROPSZ * CROPSZ) + (size_t)r0 * CROPSZ + c0;
#pragma unroll
    for (int i = 0; i < 5; ++i) {
        float sy = syb + (float)i;
        float rin = (sy >= 0.f && sy <= (float)(HF - 1)) ? 1.f : 0.f;
        float4 o;
        o.x = (hz[i][0] * omwy + hz[i + 1][0] * wy) * rin * cin[0];
        o.y = (hz[i][1] * omwy + hz[i + 1][1] * wy) * rin * cin[1];
        o.z = (hz[i][2] * omwy + hz[i + 1][2] * wy) * rin * cin[2];
        o.w = (hz[i][3] * omwy + hz[i + 1][3] * wy) * rin * cin[3];
        *(float4*)(out_crops + ob + (size_t)i * CROPSZ) = o;
    }
}

extern "C" void kernel_launch(void* const* d_in, const int* in_sizes, int n_in,
                              void* d_out, int out_size, void* d_ws, size_t ws_size,
                              hipStream_t stream) {
    const float* full = (const float*)d_in[0];
    const float* w1   = (const float*)d_in[1];
    const float* b1   = (const float*)d_in[2];
    const float* w2   = (const float*)d_in[3];
    const float* b2   = (const float*)d_in[4];

    char* ws = (char*)d_ws;
    float* imgs = (float*)(ws + OFF_IMGS);
    float* cms  = (float*)(ws + OFF_CMS);
    int* counts = (int*)(ws + OFF_CNT);
    float* ws_cx = (float*)(ws + OFF_CX);
    float* ws_cy = (float*)(ws + OFF_CY);
    float* ws_v  = (float*)(ws + OFF_VLD);
    unsigned long long* cand = (unsigned long long*)(ws + OFF_CAND);

    float* out = (float*)d_out;
    float* out_crops = out + OUT_CROPS;
    float* out_off   = out + OUT_OFFS;
    float* out_vals  = out + OUT_VALS;
    float* out_valid = out + OUT_VALID;

    hipLaunchKernelGGL(resize_kernel, dim3(128, 16), dim3(256), 0, stream,
                       full, imgs, counts);

    hipLaunchKernelGGL(conv_fused2_kernel, dim3(64, 32), dim3(256), 0, stream,
                       imgs, w1, b1, w2, b2, cms);

    hipLaunchKernelGGL(peak_topk_kernel, dim3(256), dim3(256), 0, stream,
                       cms, counts, cand, out_off, out_vals, out_valid,
                       ws_cx, ws_cy, ws_v);

    hipLaunchKernelGGL(crop_kernel, dim3(2560), dim3(256), 0, stream,
                       full, ws_cx, ws_cy, ws_v, out_crops);
}